// Round 7
// baseline (182.054 us; speedup 1.0000x reference)
//
#include <hip/hip_runtime.h>

#define HH 96
#define WW 128
#define PP 9
#define RAD 4
#define YT 2                    // y rows per block
#define CCH 8                   // channels per chunk
#define NCHUNK 16
#define TDI 3                   // di values per block (grid.z splits di 3-way)
#define ROWS2 (YT + TDI - 1)    // 4 in2 rows staged
#define GS 137                  // granule stride per row (136 + 1 pad)
#define NG2 (ROWS2 * 136)       // 544 in2 granules per chunk
#define NT 384                  // 2 * 3 * 64 threads = 6 full waves
#define PX 2                    // x pixels per thread
#define CHS (HH * WW)           // channel plane stride
#define CSTEP (CCH * CHS)       // global stride per chunk

// clang's amdgcn builtins use __fp16 vectors ('h' encoding), not _Float16.
typedef __fp16 h2v __attribute__((ext_vector_type(2)));
union HU { unsigned int u; h2v h; };

__device__ __forceinline__ unsigned int pk(float a, float b) {
    HU r; r.h = __builtin_amdgcn_cvt_pkrtz(a, b); return r.u;
}
__device__ __forceinline__ float dot2(unsigned int a, unsigned int b, float c) {
    HU ua, ub; ua.u = a; ub.u = b;
    return __builtin_amdgcn_fdot2(ua.h, ub.h, c, false);
}
// granule-level XOR swizzle: spreads strided granule reads across bank groups
__device__ __forceinline__ int swz(int g) { return g ^ ((g >> 3) & 7); }

__global__ __launch_bounds__(NT, 4)
void corr_kernel(const float* __restrict__ in1, const float* __restrict__ in2,
                 float* __restrict__ out)
{
    // double-buffered LDS; one barrier per chunk
    __shared__ uint4 s2[2][ROWS2 * GS];   // in2 window rows
    __shared__ uint4 s1[2][YT * GS];      // in1 rows

    const int tid = threadIdx.x;
    const int y0  = blockIdx.x * YT;
    const int b   = blockIdx.y;
    const int dib = blockIdx.z * TDI;

    // compute role: (yl, di3, xg); one wave = one (yl,di3) x 64 xg
    const int yl  = tid / (TDI * 64);
    const int rem = tid - yl * (TDI * 64);
    const int di3 = rem >> 6;
    const int xg  = rem & 63;
    const int x0  = xg * PX;

    const float* b1 = in1 + (size_t)b * 128 * CHS;
    const float* b2 = in2 + (size_t)b * 128 * CHS;

    // ---- staging descriptors (verified rounds 5/6) ----
    // k=0: in2 granule s = tid (< 544)
    const int r0  = tid / 136;
    const int l0  = tid - r0 * 136;
    const int gy0 = y0 - RAD + dib + r0;
    const int gx0 = l0 - RAD;
    const bool v0 = ((unsigned)gy0 < HH) && ((unsigned)gx0 < WW);
    const float* p0 = b2 + (gy0 * WW + gx0);
    const int d0  = r0 * GS + swz(l0);                 // -> s2

    // k=1: s = tid + 384: in2 if s<544 (tid<160) else in1 t = s-544 in [0,224)
    const int s1i   = tid + NT;
    const bool k1in2 = (s1i < NG2);
    const int r1a = s1i / 136;
    const int l1a = s1i - r1a * 136;
    const int gy1 = y0 - RAD + dib + r1a;
    const int gx1 = l1a - RAD;
    const int t1  = s1i - NG2;
    const int r1b = t1 >> 7;
    const int x1b = t1 & 127;
    const bool v1 = k1in2 ? (((unsigned)gy1 < HH) && ((unsigned)gx1 < WW)) : true;
    const float* p1 = k1in2 ? (b2 + (gy1 * WW + gx1))
                            : (b1 + ((y0 + r1b) * WW + x1b));
    const int d1  = k1in2 ? (r1a * GS + swz(l1a)) : (r1b * GS + swz(x1b));

    // k=2: tid<32: in1 row 1, x = 96+tid
    const bool act2 = (tid < 32);
    const float* p2 = b1 + ((y0 + 1) * WW + (96 + tid));
    const int d2  = GS + swz(96 + tid);                // -> s1 row 1

    float acc[PP][PX];
    #pragma unroll
    for (int j = 0; j < PP; ++j) { acc[j][0] = 0.f; acc[j][1] = 0.f; }

    // prefetch registers — inline #pragma unroll loops with literal trip
    // counts compile to static indices (round-6 evidence); round 5's spill
    // was a macro-_Pragma failure, not an array problem.
    float f0[8], f1[8], f2[8];

    // ---- prologue: load + stage chunk 0 into buf 0 ----
    #pragma unroll
    for (int j = 0; j < 8; ++j) f0[j] = v0 ? p0[j * CHS] : 0.f;
    #pragma unroll
    for (int j = 0; j < 8; ++j) f1[j] = v1 ? p1[j * CHS] : 0.f;
    if (act2) {
        #pragma unroll
        for (int j = 0; j < 8; ++j) f2[j] = p2[j * CHS];
    }
    {
        uint4 g;
        g.x = pk(f0[0], f0[1]); g.y = pk(f0[2], f0[3]);
        g.z = pk(f0[4], f0[5]); g.w = pk(f0[6], f0[7]);
        s2[0][d0] = g;
        g.x = pk(f1[0], f1[1]); g.y = pk(f1[2], f1[3]);
        g.z = pk(f1[4], f1[5]); g.w = pk(f1[6], f1[7]);
        if (k1in2) s2[0][d1] = g; else s1[0][d1] = g;
        if (act2) {
            g.x = pk(f2[0], f2[1]); g.y = pk(f2[2], f2[3]);
            g.z = pk(f2[4], f2[5]); g.w = pk(f2[6], f2[7]);
            s1[0][d2] = g;
        }
    }
    __syncthreads();

    for (int cc = 0; cc < NCHUNK; ++cc) {
        const int buf = cc & 1;
        const bool more = (cc + 1 < NCHUNK);
        const int co = (cc + 1) * CSTEP;

        // ---- T14 issue-early: fire next chunk's global loads now ----
        if (more) {
            #pragma unroll
            for (int j = 0; j < 8; ++j) f0[j] = v0 ? p0[co + j * CHS] : 0.f;
            #pragma unroll
            for (int j = 0; j < 8; ++j) f1[j] = v1 ? p1[co + j * CHS] : 0.f;
            if (act2) {
                #pragma unroll
                for (int j = 0; j < 8; ++j) f2[j] = p2[co + j * CHS];
            }
        }

        // ---- compute from LDS (latency of the loads above hides here) ----
        {
            const uint4* ar = &s1[buf][yl * GS];
            const uint4 a0 = ar[swz(x0)];
            const uint4 a1 = ar[swz(x0 + 1)];
            const uint4* r2 = &s2[buf][(yl + di3) * GS];
            #pragma unroll
            for (int w = 0; w < PX + PP - 1; ++w) {
                const uint4 v = r2[swz(x0 + w)];
                if (w <= PP - 1) {
                    float t = acc[w][0];
                    t = dot2(v.x, a0.x, t); t = dot2(v.y, a0.y, t);
                    t = dot2(v.z, a0.z, t); t = dot2(v.w, a0.w, t);
                    acc[w][0] = t;
                }
                if (w >= 1) {
                    float t = acc[w - 1][1];
                    t = dot2(v.x, a1.x, t); t = dot2(v.y, a1.y, t);
                    t = dot2(v.z, a1.z, t); t = dot2(v.w, a1.w, t);
                    acc[w - 1][1] = t;
                }
            }
        }

        // ---- write-late: land chunk cc+1 into the other buffer ----
        if (more) {
            uint4 g;
            g.x = pk(f0[0], f0[1]); g.y = pk(f0[2], f0[3]);
            g.z = pk(f0[4], f0[5]); g.w = pk(f0[6], f0[7]);
            s2[buf ^ 1][d0] = g;
            g.x = pk(f1[0], f1[1]); g.y = pk(f1[2], f1[3]);
            g.z = pk(f1[4], f1[5]); g.w = pk(f1[6], f1[7]);
            if (k1in2) s2[buf ^ 1][d1] = g; else s1[buf ^ 1][d1] = g;
            if (act2) {
                g.x = pk(f2[0], f2[1]); g.y = pk(f2[2], f2[3]);
                g.z = pk(f2[4], f2[5]); g.w = pk(f2[6], f2[7]);
                s1[buf ^ 1][d2] = g;
            }
        }
        __syncthreads();
        // barrier orders: my writes to buf^1 are visible before anyone
        // computes chunk cc+1 from buf^1; readers of buf finished before
        // the NEXT iteration's writes touch buf.
    }

    // epilogue: disjoint stores (this block owns di = dib..dib+2)
    const int y  = y0 + yl;
    const int di = dib + di3;
    #pragma unroll
    for (int dj = 0; dj < PP; ++dj) {
        float* op = out + ((((size_t)(b * PP + di)) * PP + dj) * HH + y) * WW + x0;
        *reinterpret_cast<float2*>(op) = make_float2(acc[dj][0], acc[dj][1]);
    }
}

extern "C" void kernel_launch(void* const* d_in, const int* in_sizes, int n_in,
                              void* d_out, int out_size, void* d_ws, size_t ws_size,
                              hipStream_t stream) {
    const float* in1 = (const float*)d_in[0];
    const float* in2 = (const float*)d_in[1];
    float* out = (float*)d_out;
    dim3 grid(HH / YT, 8, 3);   // 48 x 8 x 3 = 1152 blocks (~4.5/CU)
    dim3 block(NT);
    corr_kernel<<<grid, block, 0, stream>>>(in1, in2, out);
}

// Round 9
// 180.326 us; speedup vs baseline: 1.0096x; 1.0096x over previous
//
#include <hip/hip_runtime.h>

#define HH 96
#define WW 128
#define PP 9
#define RAD 4
#define YT 2                    // y rows per block
#define CCH 8                   // channels per chunk
#define NCHUNK 16
#define TDI 3                   // di values per block
#define ROWS2 (YT + TDI - 1)    // 4 in2 rows staged
#define WB 64                   // x-tile width per block (x-split x2)
#define HALO (WB + 2 * RAD)     // 72 in2 granules per row
#define GS2 73                  // in2 granule row stride (+1 pad)
#define GS1 65                  // in1 granule row stride (+1 pad)
#define NPAIR2 (ROWS2 * (HALO / 2))   // 144 in2 granule-pairs
#define NPAIR1 (YT * (WB / 2))        // 64 in1 granule-pairs
#define NT 192                  // 3 di * 2 y * 32 xg = 3 full waves
#define CHS (HH * WW)           // channel plane stride
#define CSTEP (CCH * CHS)       // global stride per chunk

// clang's amdgcn builtins use __fp16 vectors ('h' encoding), not _Float16.
typedef __fp16 h2v __attribute__((ext_vector_type(2)));
union HU { unsigned int u; h2v h; };

__device__ __forceinline__ unsigned int pk(float a, float b) {
    HU r; r.h = __builtin_amdgcn_cvt_pkrtz(a, b); return r.u;
}
__device__ __forceinline__ float dot2(unsigned int a, unsigned int b, float c) {
    HU ua, ub; ua.u = a; ub.u = b;
    return __builtin_amdgcn_fdot2(ua.h, ub.h, c, false);
}
// granule-level XOR swizzle: spreads strided granule reads across bank groups
__device__ __forceinline__ int swz(int g) { return g ^ ((g >> 3) & 7); }

__global__ __launch_bounds__(NT, 6)
void corr_kernel(const float* __restrict__ in1, const float* __restrict__ in2,
                 float* __restrict__ out)
{
    // double-buffered LDS; one barrier per chunk (13.5 KB total)
    __shared__ uint4 s2[2][ROWS2 * GS2];   // in2 window rows
    __shared__ uint4 s1[2][YT * GS1];      // in1 rows

    const int tid = threadIdx.x;
    const int by  = blockIdx.x >> 1;       // y-tile
    const int bx  = blockIdx.x & 1;        // x-tile
    const int y0  = by * YT;
    const int x0b = bx * WB;
    const int b   = blockIdx.y;
    const int dib = blockIdx.z * TDI;

    // compute role: di3 wave-uniform, then yl, xg
    const int di3 = tid >> 6;              // 0..2 (uniform per wave)
    const int yl  = (tid >> 5) & 1;        // 0..1
    const int xg  = tid & 31;              // 0..31
    const int x0l = 2 * xg;                // local x of first pixel

    const float* b1 = in1 + (size_t)b * 128 * CHS;
    const float* b2 = in2 + (size_t)b * 128 * CHS;

    // ---- staging descriptors: granule-PAIR tasks (208 total) ----
    // RAD=4 even + gx even => both pair halves share one validity predicate.
    // task0 = tid (0..191); task1 = tid+192 (only tid<16)
    const float* tp0; int dA0, dB0; bool tv0, t0is2;
    if (tid < NPAIR2) {                    // in2: row = tid/36, pp = tid%36
        const int row = tid / 36;
        const int pp  = tid - row * 36;
        const int gy  = y0 - RAD + dib + row;
        const int gx  = x0b + 2 * pp - RAD;
        t0is2 = true;
        tv0   = ((unsigned)gy < HH) && ((unsigned)gx < WW);
        tp0   = b2 + (gy * WW + gx);
        dA0   = row * GS2 + swz(2 * pp);
        dB0   = row * GS2 + swz(2 * pp + 1);
    } else {                               // in1: u = tid-144 in [0,48)
        const int u   = tid - NPAIR2;
        const int row = u >> 5;
        const int pp  = u & 31;
        t0is2 = false;
        tv0   = true;
        tp0   = b1 + ((y0 + row) * WW + x0b + 2 * pp);
        dA0   = row * GS1 + swz(2 * pp);
        dB0   = row * GS1 + swz(2 * pp + 1);
    }
    const bool act1 = (tid < 16);          // in1 row 1, pairs 16..31
    const float* tp1 = b1 + ((y0 + 1) * WW + x0b + 2 * (16 + tid));
    const int dA1 = GS1 + swz(2 * (16 + tid));
    const int dB1 = GS1 + swz(2 * (16 + tid) + 1);

    float acc[PP][2];
    #pragma unroll
    for (int j = 0; j < PP; ++j) { acc[j][0] = 0.f; acc[j][1] = 0.f; }

    for (int cc = 0; cc < NCHUNK; ++cc) {
        const int buf = cc & 1;
        const int co  = cc * CSTEP;

        // ---- stage chunk cc (transient regs only; float2 x-pair loads) ----
        {
            float2 f[8];
            #pragma unroll
            for (int j = 0; j < 8; ++j)
                f[j] = tv0 ? *reinterpret_cast<const float2*>(tp0 + co + j * CHS)
                           : make_float2(0.f, 0.f);
            uint4 gA, gB;
            gA.x = pk(f[0].x, f[1].x); gA.y = pk(f[2].x, f[3].x);
            gA.z = pk(f[4].x, f[5].x); gA.w = pk(f[6].x, f[7].x);
            gB.x = pk(f[0].y, f[1].y); gB.y = pk(f[2].y, f[3].y);
            gB.z = pk(f[4].y, f[5].y); gB.w = pk(f[6].y, f[7].y);
            if (t0is2) { s2[buf][dA0] = gA; s2[buf][dB0] = gB; }
            else       { s1[buf][dA0] = gA; s1[buf][dB0] = gB; }
        }
        if (act1) {
            float2 f[8];
            #pragma unroll
            for (int j = 0; j < 8; ++j)
                f[j] = *reinterpret_cast<const float2*>(tp1 + co + j * CHS);
            uint4 gA, gB;
            gA.x = pk(f[0].x, f[1].x); gA.y = pk(f[2].x, f[3].x);
            gA.z = pk(f[4].x, f[5].x); gA.w = pk(f[6].x, f[7].x);
            gB.x = pk(f[0].y, f[1].y); gB.y = pk(f[2].y, f[3].y);
            gB.z = pk(f[4].y, f[5].y); gB.w = pk(f[6].y, f[7].y);
            s1[buf][dA1] = gA; s1[buf][dB1] = gB;
        }
        __syncthreads();

        // ---- compute from LDS ----
        {
            const uint4* ar = &s1[buf][yl * GS1];
            const uint4 a0 = ar[swz(x0l)];
            const uint4 a1 = ar[swz(x0l + 1)];
            const uint4* r2 = &s2[buf][(yl + di3) * GS2];
            #pragma unroll
            for (int w = 0; w < PP + 1; ++w) {      // 10-granule window
                const uint4 v = r2[swz(x0l + w)];
                if (w <= PP - 1) {
                    float t = acc[w][0];
                    t = dot2(v.x, a0.x, t); t = dot2(v.y, a0.y, t);
                    t = dot2(v.z, a0.z, t); t = dot2(v.w, a0.w, t);
                    acc[w][0] = t;
                }
                if (w >= 1) {
                    float t = acc[w - 1][1];
                    t = dot2(v.x, a1.x, t); t = dot2(v.y, a1.y, t);
                    t = dot2(v.z, a1.z, t); t = dot2(v.w, a1.w, t);
                    acc[w - 1][1] = t;
                }
            }
        }
        // no trailing barrier: next stage writes buf^1; the sync in the next
        // iteration orders compute(cc) before stage(cc+2) overwrites buf.
    }

    // ---- epilogue: disjoint float2 stores ----
    const int y  = y0 + yl;
    const int di = dib + di3;
    const int xo = x0b + x0l;
    #pragma unroll
    for (int dj = 0; dj < PP; ++dj) {
        float* op = out + ((((size_t)(b * PP + di)) * PP + dj) * HH + y) * WW + xo;
        *reinterpret_cast<float2*>(op) = make_float2(acc[dj][0], acc[dj][1]);
    }
}

extern "C" void kernel_launch(void* const* d_in, const int* in_sizes, int n_in,
                              void* d_out, int out_size, void* d_ws, size_t ws_size,
                              hipStream_t stream) {
    const float* in1 = (const float*)d_in[0];
    const float* in2 = (const float*)d_in[1];
    float* out = (float*)d_out;
    dim3 grid((HH / YT) * 2, 8, 3);   // 96 x 8 x 3 = 2304 blocks = 9/CU uniform
    dim3 block(NT);
    corr_kernel<<<grid, block, 0, stream>>>(in1, in2, out);
}

// Round 12
// 168.592 us; speedup vs baseline: 1.0798x; 1.0696x over previous
//
#include <hip/hip_runtime.h>

#define HH 96
#define WW 128
#define PP 9
#define RAD 4
#define YT 2                    // y rows per block
#define CCH 8                   // channels per chunk
#define NCHUNK 16
#define ROWS2 (YT + PP - 1)     // 10 in2 rows staged (all 9 di in-block)
#define WB 64                   // x-tile width per block
#define HALO (WB + 2 * RAD)     // 72 in2 granules per row
#define GS2 73                  // in2 granule row stride (+1 pad)
#define GS1 65                  // in1 granule row stride (+1 pad)
#define NP2 (ROWS2 * (HALO / 2))    // 360 in2 granule-pairs
#define NP1 (YT * (WB / 2))         // 64 in1 granule-pairs
#define NTASK (NP2 + NP1)           // 424 staging tasks (<= NT)
#define NT 576                  // 9 waves: di = tid>>6 (wave-uniform)
#define CHS (HH * WW)           // channel plane stride
#define CSTEP (CCH * CHS)       // global stride per chunk

// clang's amdgcn builtins use __fp16 vectors ('h' encoding), not _Float16.
typedef __fp16 h2v __attribute__((ext_vector_type(2)));
union HU { unsigned int u; h2v h; };

__device__ __forceinline__ unsigned int pk(float a, float b) {
    HU r; r.h = __builtin_amdgcn_cvt_pkrtz(a, b); return r.u;
}
__device__ __forceinline__ float dot2(unsigned int a, unsigned int b, float c) {
    HU ua, ub; ua.u = a; ub.u = b;
    return __builtin_amdgcn_fdot2(ua.h, ub.h, c, false);
}
// granule-level XOR swizzle: spreads strided granule reads across bank groups
__device__ __forceinline__ int swz(int g) { return g ^ ((g >> 3) & 7); }

__global__ __launch_bounds__(NT, 7)
void corr_kernel(const float* __restrict__ in1, const float* __restrict__ in2,
                 float* __restrict__ out)
{
    // double-buffered LDS; one barrier per chunk (26.9 KB -> 3 blocks/CU easily)
    __shared__ uint4 s2[2][ROWS2 * GS2];   // in2 window rows (10 per buf)
    __shared__ uint4 s1[2][YT * GS1];      // in1 rows

    const int tid = threadIdx.x;
    const int by  = blockIdx.x >> 1;       // y-tile
    const int bx  = blockIdx.x & 1;        // x-tile
    const int y0  = by * YT;
    const int x0b = bx * WB;
    const int b   = blockIdx.y;

    // compute role: di wave-uniform (tid>>6), then yl, xg
    const int di  = tid >> 6;              // 0..8
    const int yl  = (tid >> 5) & 1;        // 0..1
    const int xg  = tid & 31;              // 0..31
    const int x0l = 2 * xg;                // local x of first pixel

    const float* b1 = in1 + (size_t)b * 128 * CHS;
    const float* b2 = in2 + (size_t)b * 128 * CHS;

    // ---- staging task: one granule-PAIR per thread (424 tasks) ----
    // RAD=4 even + gx even => both pair halves share one validity predicate.
    const bool act = (tid < NTASK);
    const float* tp = b1; int dA = 0, dB = 0; bool tv = false, is2 = false;
    if (tid < NP2) {                       // in2: row = tid/36, pair = tid%36
        const int r  = tid / 36;
        const int p  = tid - r * 36;
        const int gy = y0 - RAD + r;
        const int gx = x0b + 2 * p - RAD;
        is2 = true;
        tv  = ((unsigned)gy < HH) && ((unsigned)gx < WW);
        tp  = b2 + (gy * WW + gx);
        dA  = r * GS2 + swz(2 * p);
        dB  = r * GS2 + swz(2 * p + 1);
    } else if (act) {                      // in1: u in [0,64)
        const int u = tid - NP2;
        const int r = u >> 5;
        const int p = u & 31;
        tv  = true;
        tp  = b1 + ((y0 + r) * WW + x0b + 2 * p);
        dA  = r * GS1 + swz(2 * p);
        dB  = r * GS1 + swz(2 * p + 1);
    }

    float acc[PP][2];
    #pragma unroll
    for (int j = 0; j < PP; ++j) { acc[j][0] = 0.f; acc[j][1] = 0.f; }

    for (int cc = 0; cc < NCHUNK; ++cc) {
        const int buf = cc & 1;
        const int co  = cc * CSTEP;

        // ---- stage chunk cc (transient regs only; float2 x-pair loads) ----
        if (act) {
            float2 f[8];
            #pragma unroll
            for (int j = 0; j < 8; ++j)
                f[j] = tv ? *reinterpret_cast<const float2*>(tp + co + j * CHS)
                          : make_float2(0.f, 0.f);
            uint4 gA, gB;
            gA.x = pk(f[0].x, f[1].x); gA.y = pk(f[2].x, f[3].x);
            gA.z = pk(f[4].x, f[5].x); gA.w = pk(f[6].x, f[7].x);
            gB.x = pk(f[0].y, f[1].y); gB.y = pk(f[2].y, f[3].y);
            gB.z = pk(f[4].y, f[5].y); gB.w = pk(f[6].y, f[7].y);
            if (is2) { s2[buf][dA] = gA; s2[buf][dB] = gB; }
            else     { s1[buf][dA] = gA; s1[buf][dB] = gB; }
        }
        __syncthreads();

        // ---- compute from LDS (all 9 di live in this block) ----
        {
            const uint4* ar = &s1[buf][yl * GS1];
            const uint4 a0 = ar[swz(x0l)];
            const uint4 a1 = ar[swz(x0l + 1)];
            const uint4* r2 = &s2[buf][(yl + di) * GS2];
            #pragma unroll
            for (int w = 0; w < PP + 1; ++w) {      // 10-granule window
                const uint4 v = r2[swz(x0l + w)];
                if (w <= PP - 1) {
                    float t = acc[w][0];
                    t = dot2(v.x, a0.x, t); t = dot2(v.y, a0.y, t);
                    t = dot2(v.z, a0.z, t); t = dot2(v.w, a0.w, t);
                    acc[w][0] = t;
                }
                if (w >= 1) {
                    float t = acc[w - 1][1];
                    t = dot2(v.x, a1.x, t); t = dot2(v.y, a1.y, t);
                    t = dot2(v.z, a1.z, t); t = dot2(v.w, a1.w, t);
                    acc[w - 1][1] = t;
                }
            }
        }
        // no trailing barrier: next stage writes buf^1; the sync in the next
        // iteration orders compute(cc) before stage(cc+2) overwrites buf.
    }

    // ---- epilogue: disjoint float2 stores ----
    const int y  = y0 + yl;
    const int xo = x0b + x0l;
    #pragma unroll
    for (int dj = 0; dj < PP; ++dj) {
        float* op = out + ((((size_t)(b * PP + di)) * PP + dj) * HH + y) * WW + xo;
        *reinterpret_cast<float2*>(op) = make_float2(acc[dj][0], acc[dj][1]);
    }
}

extern "C" void kernel_launch(void* const* d_in, const int* in_sizes, int n_in,
                              void* d_out, int out_size, void* d_ws, size_t ws_size,
                              hipStream_t stream) {
    const float* in1 = (const float*)d_in[0];
    const float* in2 = (const float*)d_in[1];
    float* out = (float*)d_out;
    dim3 grid((HH / YT) * 2, 8);   // 96 x 8 = 768 blocks = exactly 3/CU
    dim3 block(NT);
    corr_kernel<<<grid, block, 0, stream>>>(in1, in2, out);
}